// Round 2
// baseline (727.029 us; speedup 1.0000x reference)
//
#include <hip/hip_runtime.h>
#include <math.h>

#define B_ 64
#define I_ 4096
#define P_ 8      // Din
#define N_ 10
#define D_ 16
#define ND_ 160   // N*D
#define BND_ (B_*ND_)   // 10240
#define EPS_ 1e-7f

#define IPB_ 8                 // i per block
#define NBLK_ (I_ / IPB_)      // 512 blocks = exactly 2 blocks/CU on 256 CUs
#define WTILE_ (N_ * P_ * D_)  // 1280 floats of W per i (global, unpadded)
#define NSTR_ 144              // padded n-stride in LDS (floats)
#define ILSTR_ (N_ * NSTR_)    // 1440 floats per i in LDS
#define RBLK_ 320              // blocks participating in the distributed reduce

// DPP cross-lane value fetch on the VALU pipe (no DS traffic).
// 0xB1 quad_perm xor1; 0x4E quad_perm xor2; 0x141 row_half_mirror (xor4 once
// bits0-1 uniform); 0x140 row_mirror (xor8 once bits0-2 uniform).
template<int CTRL>
__device__ __forceinline__ float dpp_bcast(float v) {
    int r = __builtin_amdgcn_update_dpp(0, __float_as_int(v), CTRL, 0xF, 0xF, true);
    return __int_as_float(r);
}

// Round-14: SINGLE-KERNEL FUSION (theory: the ~100 us not in our kernels is
// the 6-dispatch serial chain -- 5 dependency gaps + 6 ramps + W staged 3x).
// Non-cooperative grid barrier; safe because the launch is an exact fit:
// 512 blocks @ __launch_bounds__(256,2) = 2 blocks/CU x 256 CU, LDS 46KBx2,
// VGPR<=256 -> all blocks co-resident. NOT hipLaunchCooperativeKernel
// (R11: that API deadlocked under graph capture).
//  - Monotonic counter barrier: works from ANY initial counter value (poison
//    or rocprof replay without the memset node) -- target = (old/512+1)*512.
//  - ~20 ms s_memrealtime timeout breaks the spin (fails visibly, no hang).
//  - __threadfence() on both sides (L2 writeback / invalidate) for cross-XCD
//    part/Vc visibility.
__device__ __forceinline__ void gridbar(unsigned* cnt, int slot) {
    __threadfence();                       // release: my stores -> device
    __syncthreads();                       // block's stores all issued+fenced
    if (threadIdx.x == 0) {
        unsigned old = atomicAdd(&cnt[slot], 1u);              // device scope
        unsigned tgt = (old / (unsigned)NBLK_ + 1u) * (unsigned)NBLK_;
        long long t0 = (long long)__builtin_amdgcn_s_memrealtime();
        while (__hip_atomic_load(&cnt[slot], __ATOMIC_RELAXED,
                                 __HIP_MEMORY_SCOPE_AGENT) < tgt) {
            __builtin_amdgcn_s_sleep(8);
            if ((long long)__builtin_amdgcn_s_memrealtime() - t0 > 2000000LL)
                break;                     // ~20 ms @ 100 MHz: fail, don't hang
        }
    }
    __syncthreads();
    __threadfence();                       // acquire: invalidate before reads
}

// __launch_bounds__(256, 2) -- R2-proven AND required for barrier safety
// (guarantees 2 blocks/CU => 512 co-resident). Do NOT tighten (R3: spill).
__global__ __launch_bounds__(256, 2)
void digitcaps_fused(const float* __restrict__ x, const float* __restrict__ W,
                     float* __restrict__ part, float* __restrict__ Vc,
                     float* __restrict__ out, unsigned* __restrict__ cnt)
{
    __shared__ float wsh[IPB_ * ILSTR_];   // 46080 B
    __shared__ float rsm[4][32];
    const int t = threadIdx.x;
    const int lane = t & 63;
    const int ds  = lane & 7;              // d-pair index: d = 2ds, 2ds+1
    const int np  = (lane >> 3) & 1;       // n-parity (owns n = np+2k)
    const int bl2 = lane >> 4;             // 0..3
    const int wv  = t >> 6;                // 0..3
    const int bb  = wv * 16 + bl2 * 4;     // first of this thread's 4 b's
    const int i0  = blockIdx.x * IPB_;

    // ---- stage W[i0..i0+8) into padded LDS ONCE (was 3x): 10 float4/thread
    {
        const float4* __restrict__ Wg = (const float4*)(W + (size_t)i0 * WTILE_);
        float4* __restrict__ Ws = (float4*)wsh;
#pragma unroll
        for (int c0 = 0; c0 < (IPB_ * WTILE_) / (4 * 256); ++c0) {  // 10
            int c  = c0 * 256 + t;
            int il = c / 320;
            int r  = c - il * 320;
            int n  = r >> 5;
            int s  = r & 31;
            Ws[il * 360 + n * 36 + s] = Wg[c];
        }
    }
    __syncthreads();   // W staged

    for (int it = 0; it < 3; ++it) {
        const bool uni = (it == 0);

        float vc[4][5][2];
        if (!uni) {
#pragma unroll
            for (int j = 0; j < 4; ++j)
#pragma unroll
                for (int k = 0; k < 5; ++k) {
                    const float2* vp = (const float2*)(Vc + (size_t)(bb + j) * ND_
                                                       + (np + 2 * k) * D_ + 2 * ds);
                    float2 v = *vp;
                    vc[j][k][0] = v.x; vc[j][k][1] = v.y;
                }
        }

        float acc[4][5][2];
#pragma unroll
        for (int j = 0; j < 4; ++j)
#pragma unroll
            for (int k = 0; k < 5; ++k) { acc[j][k][0] = 0.f; acc[j][k][1] = 0.f; }

        // preload x for il=0 (L2-hot after iteration 0)
        float xv[4][P_];
#pragma unroll
        for (int j = 0; j < 4; ++j) {
            const float4* xp = (const float4*)(x + ((size_t)(bb + j) * I_ + i0) * P_);
            float4 a0 = xp[0], a1 = xp[1];
            xv[j][0]=a0.x; xv[j][1]=a0.y; xv[j][2]=a0.z; xv[j][3]=a0.w;
            xv[j][4]=a1.x; xv[j][5]=a1.y; xv[j][6]=a1.z; xv[j][7]=a1.w;
        }

#pragma unroll 1
        for (int il = 0; il < IPB_; ++il) {
            const float* __restrict__ Wb = wsh + il * ILSTR_ + np * NSTR_ + 2 * ds;

            // u_hat fragments tv[j][k][d]: 40 ds_read_b64, 320 FMA
            float tv[4][5][2];
#pragma unroll
            for (int k = 0; k < 5; ++k) {
#pragma unroll
                for (int j = 0; j < 4; ++j) { tv[j][k][0] = 0.f; tv[j][k][1] = 0.f; }
#pragma unroll
                for (int p = 0; p < P_; ++p) {
                    float2 w = *(const float2*)(Wb + k * 2 * NSTR_ + p * D_);
#pragma unroll
                    for (int j = 0; j < 4; ++j) {
                        tv[j][k][0] = fmaf(w.x, xv[j][p], tv[j][k][0]);
                        tv[j][k][1] = fmaf(w.y, xv[j][p], tv[j][k][1]);
                    }
                }
            }

            // prefetch x for il+1
            float xn[4][P_];
            if (il + 1 < IPB_) {
#pragma unroll
                for (int j = 0; j < 4; ++j) {
                    const float4* xp = (const float4*)(x + ((size_t)(bb + j) * I_
                                                            + i0 + il + 1) * P_);
                    float4 a0 = xp[0], a1 = xp[1];
                    xn[j][0]=a0.x; xn[j][1]=a0.y; xn[j][2]=a0.z; xn[j][3]=a0.w;
                    xn[j][4]=a1.x; xn[j][5]=a1.y; xn[j][6]=a1.z; xn[j][7]=a1.w;
                }
            }

            if (uni) {
#pragma unroll
                for (int j = 0; j < 4; ++j)
#pragma unroll
                    for (int k = 0; k < 5; ++k) {
                        acc[j][k][0] += tv[j][k][0];
                        acc[j][k][1] += tv[j][k][1];
                    }
            } else {
#pragma unroll
                for (int j = 0; j < 4; ++j) {
                    float e[5];
                    float m = -1e30f;
#pragma unroll
                    for (int k = 0; k < 5; ++k) {
                        float l = fmaf(tv[j][k][1], vc[j][k][1],
                                       tv[j][k][0] * vc[j][k][0]);
                        l += dpp_bcast<0xB1>(l);
                        l += dpp_bcast<0x4E>(l);
                        l += dpp_bcast<0x141>(l);   // full d-dot across 8 ds lanes
                        e[k] = l;
                        m = fmaxf(m, l);
                    }
                    m = fmaxf(m, dpp_bcast<0x140>(m));   // max over other parity
                    float se = 0.f;
#pragma unroll
                    for (int k = 0; k < 5; ++k) { e[k] = __expf(e[k] - m); se += e[k]; }
                    se += dpp_bcast<0x140>(se);
                    float inv = 1.f / se;
#pragma unroll
                    for (int k = 0; k < 5; ++k) {
                        float cn = e[k] * inv;
                        acc[j][k][0] = fmaf(cn, tv[j][k][0], acc[j][k][0]);
                        acc[j][k][1] = fmaf(cn, tv[j][k][1], acc[j][k][1]);
                    }
                }
            }

            if (il + 1 < IPB_) {
#pragma unroll
                for (int j = 0; j < 4; ++j)
#pragma unroll
                    for (int p = 0; p < P_; ++p) xv[j][p] = xn[j][p];
            }
        }

        // store partials, NATURAL layout part[blk][b][n][d]
#pragma unroll
        for (int j = 0; j < 4; ++j) {
            float* __restrict__ dst = part + (size_t)blockIdx.x * BND_
                                      + (size_t)(bb + j) * ND_ + np * D_ + 2 * ds;
#pragma unroll
            for (int k = 0; k < 5; ++k) {
                float2 s2; s2.x = acc[j][k][0]; s2.y = acc[j][k][1];
                *(float2*)(dst + k * 2 * D_) = s2;
            }
        }

        gridbar(cnt, it * 2);   // all partials visible

        // ---- distributed reduce: blocks 0..319, 32 outputs each ----
        if (blockIdx.x < RBLK_) {
            const int oi = t & 31;
            const int tp = t >> 5;             // 0..7, 64 rows each
            const int o  = blockIdx.x * 32 + oi;
            float s = 0.f;
            const float* __restrict__ p0 = part + (size_t)(tp * 64) * BND_ + o;
#pragma unroll 8
            for (int j = 0; j < 64; ++j)
                s += p0[(size_t)j * BND_];
            s += __shfl_down(s, 32);           // tp pairs within wave
            if ((t & 63) < 32) rsm[t >> 6][oi] = s;
            __syncthreads();
            if (t < 32) {
                float tot = (rsm[0][t] + rsm[1][t]) + (rsm[2][t] + rsm[3][t]);
                tot *= uni ? 0.1f : 1.0f;
                float sq = tot * tot;
                float v = tot * (sq / ((1.f + sq) * sqrtf(sq + EPS_)));
                int o2 = blockIdx.x * 32 + t;
                if (it == 0)      Vc[o2] = v;
                else if (it == 1) Vc[o2] += v;
                else              out[o2] = v;
            }
        }

        if (it < 2) gridbar(cnt, it * 2 + 1);  // Vc visible to next pass
    }
}

extern "C" void kernel_launch(void* const* d_in, const int* in_sizes, int n_in,
                              void* d_out, int out_size, void* d_ws, size_t ws_size,
                              hipStream_t stream)
{
    const float* x = (const float*)d_in[0];   // [64, 4096, 8] f32
    const float* W = (const float*)d_in[1];   // [4096, 10, 8, 16] f32
    float* out = (float*)d_out;               // [64, 10, 1, 16] f32

    // ws: part (512*10240 f = 21 MB) | Vc (10240 f) | cnt (8 u32)
    float* part = (float*)d_ws;
    float* Vc   = part + (size_t)NBLK_ * BND_;
    unsigned* cnt = (unsigned*)(Vc + BND_);

    // zero barrier counters (graph-capturable memset node; the barrier is
    // monotonic so it stays correct even if a replay skips this)
    hipMemsetAsync(cnt, 0, 8 * sizeof(unsigned), stream);

    digitcaps_fused<<<dim3(NBLK_), dim3(256), 0, stream>>>(x, W, part, Vc, out, cnt);
}

// Round 3
// 346.975 us; speedup vs baseline: 2.0953x; 2.0953x over previous
//
#include <hip/hip_runtime.h>
#include <math.h>

#define B_ 64
#define I_ 4096
#define P_ 8      // Din
#define N_ 10
#define D_ 16
#define ND_ 160   // N*D
#define BND_ (B_*ND_)   // 10240
#define EPS_ 1e-7f

#define IPB_ 8                 // i per block
#define NBLK_ (I_ / IPB_)      // 512 blocks = exactly 2 blocks/CU on 256 CUs
#define WTILE_ (N_ * P_ * D_)  // 1280 floats of W per i (global, unpadded)
#define NSTR_ 144              // padded n-stride in LDS (floats)
#define ILSTR_ (N_ * NSTR_)    // 1440 floats per i in LDS
#define RBLK_ 320              // blocks participating in the distributed reduce

// DPP cross-lane value fetch on the VALU pipe (no DS traffic).
template<int CTRL>
__device__ __forceinline__ float dpp_bcast(float v) {
    int r = __builtin_amdgcn_update_dpp(0, __float_as_int(v), CTRL, 0xF, 0xF, true);
    return __int_as_float(r);
}

// ---- agent-scope (sc1) accessors: bypass the non-coherent per-XCD L2s ----
// All cross-block data (part, Vc, cnt) moves ONLY through these -> no dirty
// lines in any private L2, no stale lines consulted -> NO cache-maintenance
// fences needed anywhere (R14 post-mortem: per-thread __threadfence walks
// were ~630 us of the 673 us kernel).
__device__ __forceinline__ void agent_store_f2(float* dst, float a, float b) {
    float2 v; v.x = a; v.y = b;
    unsigned long long u; __builtin_memcpy(&u, &v, 8);
    __hip_atomic_store((unsigned long long*)dst, u,
                       __ATOMIC_RELAXED, __HIP_MEMORY_SCOPE_AGENT);
}
__device__ __forceinline__ float2 agent_load_f2(const float* src) {
    unsigned long long u = __hip_atomic_load((unsigned long long*)src,
                       __ATOMIC_RELAXED, __HIP_MEMORY_SCOPE_AGENT);
    float2 v; __builtin_memcpy(&v, &u, 8); return v;
}
__device__ __forceinline__ float agent_load_f(const float* src) {
    return __hip_atomic_load((float*)src, __ATOMIC_RELAXED,
                             __HIP_MEMORY_SCOPE_AGENT);
}
__device__ __forceinline__ void agent_store_f(float* dst, float v) {
    __hip_atomic_store(dst, v, __ATOMIC_RELAXED, __HIP_MEMORY_SCOPE_AGENT);
}

// Fence-free grid barrier. Correct because: (1) __syncthreads() makes the
// compiler drain vmcnt(0) for every wave, so all sc1 stores are acked at the
// shared point before thread 0's ACQ_REL fetch_add; (2) all post-barrier
// shared reads are sc1 loads, so no invalidate is needed. Monotonic target
// (works from any initial counter value); ~20 ms timeout breaks instead of
// hanging (visible failure, not a wrong-silent hang).
__device__ __forceinline__ void gridbar(unsigned* cnt, int slot) {
    __syncthreads();
    if (threadIdx.x == 0) {
        unsigned old = __hip_atomic_fetch_add(&cnt[slot], 1u,
                            __ATOMIC_ACQ_REL, __HIP_MEMORY_SCOPE_AGENT);
        unsigned tgt = (old / (unsigned)NBLK_ + 1u) * (unsigned)NBLK_;
        long long t0 = (long long)__builtin_amdgcn_s_memrealtime();
        while (__hip_atomic_load(&cnt[slot], __ATOMIC_RELAXED,
                                 __HIP_MEMORY_SCOPE_AGENT) < tgt) {
            __builtin_amdgcn_s_sleep(8);
            if ((long long)__builtin_amdgcn_s_memrealtime() - t0 > 2000000LL)
                break;                     // ~20 ms @ 100 MHz: fail, don't hang
        }
    }
    __syncthreads();
}

// __launch_bounds__(256, 2) -- R2-proven AND required for barrier safety
// (512 blocks = 2/CU x 256 CU all co-resident; LDS 46KB x2 <= 160KB).
// NOT hipLaunchCooperativeKernel (R11: deadlocked under graph capture).
__global__ __launch_bounds__(256, 2)
void digitcaps_fused(const float* __restrict__ x, const float* __restrict__ W,
                     float* __restrict__ part, float* __restrict__ Vc,
                     float* __restrict__ out, unsigned* __restrict__ cnt)
{
    __shared__ float wsh[IPB_ * ILSTR_];   // 46080 B
    __shared__ float rsm[4][32];
    const int t = threadIdx.x;
    const int lane = t & 63;
    const int ds  = lane & 7;              // d-pair index: d = 2ds, 2ds+1
    const int np  = (lane >> 3) & 1;       // n-parity (owns n = np+2k)
    const int bl2 = lane >> 4;             // 0..3
    const int wv  = t >> 6;                // 0..3
    const int bb  = wv * 16 + bl2 * 4;     // first of this thread's 4 b's
    const int i0  = blockIdx.x * IPB_;

    // ---- stage W[i0..i0+8) into padded LDS ONCE: 10 float4/thread ----
    {
        const float4* __restrict__ Wg = (const float4*)(W + (size_t)i0 * WTILE_);
        float4* __restrict__ Ws = (float4*)wsh;
#pragma unroll
        for (int c0 = 0; c0 < (IPB_ * WTILE_) / (4 * 256); ++c0) {  // 10
            int c  = c0 * 256 + t;
            int il = c / 320;
            int r  = c - il * 320;
            int n  = r >> 5;
            int s  = r & 31;
            Ws[il * 360 + n * 36 + s] = Wg[c];
        }
    }
    __syncthreads();   // W staged

    float vprev = 0.f;   // reducer-thread register copy of Vc[o2] (same
                         // thread owns the same output every iteration)

    for (int it = 0; it < 3; ++it) {
        const bool uni = (it == 0);

        float vc[4][5][2];
        if (!uni) {
#pragma unroll
            for (int j = 0; j < 4; ++j)
#pragma unroll
                for (int k = 0; k < 5; ++k) {
                    float2 v = agent_load_f2(Vc + (size_t)(bb + j) * ND_
                                             + (np + 2 * k) * D_ + 2 * ds);
                    vc[j][k][0] = v.x; vc[j][k][1] = v.y;
                }
        }

        float acc[4][5][2];
#pragma unroll
        for (int j = 0; j < 4; ++j)
#pragma unroll
            for (int k = 0; k < 5; ++k) { acc[j][k][0] = 0.f; acc[j][k][1] = 0.f; }

        // preload x for il=0
        float xv[4][P_];
#pragma unroll
        for (int j = 0; j < 4; ++j) {
            const float4* xp = (const float4*)(x + ((size_t)(bb + j) * I_ + i0) * P_);
            float4 a0 = xp[0], a1 = xp[1];
            xv[j][0]=a0.x; xv[j][1]=a0.y; xv[j][2]=a0.z; xv[j][3]=a0.w;
            xv[j][4]=a1.x; xv[j][5]=a1.y; xv[j][6]=a1.z; xv[j][7]=a1.w;
        }

#pragma unroll 1
        for (int il = 0; il < IPB_; ++il) {
            const float* __restrict__ Wb = wsh + il * ILSTR_ + np * NSTR_ + 2 * ds;

            // u_hat fragments tv[j][k][d]: 40 ds_read_b64, 320 FMA
            float tv[4][5][2];
#pragma unroll
            for (int k = 0; k < 5; ++k) {
#pragma unroll
                for (int j = 0; j < 4; ++j) { tv[j][k][0] = 0.f; tv[j][k][1] = 0.f; }
#pragma unroll
                for (int p = 0; p < P_; ++p) {
                    float2 w = *(const float2*)(Wb + k * 2 * NSTR_ + p * D_);
#pragma unroll
                    for (int j = 0; j < 4; ++j) {
                        tv[j][k][0] = fmaf(w.x, xv[j][p], tv[j][k][0]);
                        tv[j][k][1] = fmaf(w.y, xv[j][p], tv[j][k][1]);
                    }
                }
            }

            // prefetch x for il+1
            float xn[4][P_];
            if (il + 1 < IPB_) {
#pragma unroll
                for (int j = 0; j < 4; ++j) {
                    const float4* xp = (const float4*)(x + ((size_t)(bb + j) * I_
                                                            + i0 + il + 1) * P_);
                    float4 a0 = xp[0], a1 = xp[1];
                    xn[j][0]=a0.x; xn[j][1]=a0.y; xn[j][2]=a0.z; xn[j][3]=a0.w;
                    xn[j][4]=a1.x; xn[j][5]=a1.y; xn[j][6]=a1.z; xn[j][7]=a1.w;
                }
            }

            if (uni) {
#pragma unroll
                for (int j = 0; j < 4; ++j)
#pragma unroll
                    for (int k = 0; k < 5; ++k) {
                        acc[j][k][0] += tv[j][k][0];
                        acc[j][k][1] += tv[j][k][1];
                    }
            } else {
#pragma unroll
                for (int j = 0; j < 4; ++j) {
                    float e[5];
                    float m = -1e30f;
#pragma unroll
                    for (int k = 0; k < 5; ++k) {
                        float l = fmaf(tv[j][k][1], vc[j][k][1],
                                       tv[j][k][0] * vc[j][k][0]);
                        l += dpp_bcast<0xB1>(l);
                        l += dpp_bcast<0x4E>(l);
                        l += dpp_bcast<0x141>(l);   // full d-dot across 8 ds lanes
                        e[k] = l;
                        m = fmaxf(m, l);
                    }
                    m = fmaxf(m, dpp_bcast<0x140>(m));   // max over other parity
                    float se = 0.f;
#pragma unroll
                    for (int k = 0; k < 5; ++k) { e[k] = __expf(e[k] - m); se += e[k]; }
                    se += dpp_bcast<0x140>(se);
                    float inv = 1.f / se;
#pragma unroll
                    for (int k = 0; k < 5; ++k) {
                        float cn = e[k] * inv;
                        acc[j][k][0] = fmaf(cn, tv[j][k][0], acc[j][k][0]);
                        acc[j][k][1] = fmaf(cn, tv[j][k][1], acc[j][k][1]);
                    }
                }
            }

            if (il + 1 < IPB_) {
#pragma unroll
                for (int j = 0; j < 4; ++j)
#pragma unroll
                    for (int p = 0; p < P_; ++p) xv[j][p] = xn[j][p];
            }
        }

        // store partials via sc1 (bypass L2), NATURAL layout part[blk][b][n][d]
#pragma unroll
        for (int j = 0; j < 4; ++j) {
            float* __restrict__ dst = part + (size_t)blockIdx.x * BND_
                                      + (size_t)(bb + j) * ND_ + np * D_ + 2 * ds;
#pragma unroll
            for (int k = 0; k < 5; ++k)
                agent_store_f2(dst + k * 2 * D_, acc[j][k][0], acc[j][k][1]);
        }

        gridbar(cnt, it * 2);   // all partials visible (sc1-acked)

        // ---- distributed reduce: blocks 0..319, 32 outputs each ----
        if (blockIdx.x < RBLK_) {
            const int oi = t & 31;
            const int tp = t >> 5;             // 0..7, 64 rows each
            const int o  = blockIdx.x * 32 + oi;
            float s = 0.f;
            const float* __restrict__ p0 = part + (size_t)(tp * 64) * BND_ + o;
#pragma unroll 8
            for (int j = 0; j < 64; ++j)
                s += agent_load_f(p0 + (size_t)j * BND_);
            s += __shfl_down(s, 32);           // tp pairs within wave
            if ((t & 63) < 32) rsm[t >> 6][oi] = s;
            __syncthreads();
            if (t < 32) {
                float tot = (rsm[0][t] + rsm[1][t]) + (rsm[2][t] + rsm[3][t]);
                tot *= uni ? 0.1f : 1.0f;
                float sq = tot * tot;
                float v = tot * (sq / ((1.f + sq) * sqrtf(sq + EPS_)));
                int o2 = blockIdx.x * 32 + t;
                if (it == 0)      { vprev = v;      agent_store_f(Vc + o2, vprev); }
                else if (it == 1) { vprev += v;     agent_store_f(Vc + o2, vprev); }
                else              out[o2] = v;     // normal store: kernel-end
            }                                      // writeback covers host read
        }

        if (it < 2) gridbar(cnt, it * 2 + 1);  // Vc visible to next pass
    }
}

extern "C" void kernel_launch(void* const* d_in, const int* in_sizes, int n_in,
                              void* d_out, int out_size, void* d_ws, size_t ws_size,
                              hipStream_t stream)
{
    const float* x = (const float*)d_in[0];   // [64, 4096, 8] f32
    const float* W = (const float*)d_in[1];   // [4096, 10, 8, 16] f32
    float* out = (float*)d_out;               // [64, 10, 1, 16] f32

    // ws: part (512*10240 f = 21 MB) | Vc (10240 f) | cnt (8 u32)
    float* part = (float*)d_ws;
    float* Vc   = part + (size_t)NBLK_ * BND_;
    unsigned* cnt = (unsigned*)(Vc + BND_);

    // zero barrier counters (graph-capturable; barrier is monotonic so a
    // replay that skips this node is still correct)
    hipMemsetAsync(cnt, 0, 8 * sizeof(unsigned), stream);

    digitcaps_fused<<<dim3(NBLK_), dim3(256), 0, stream>>>(x, W, part, Vc, out, cnt);
}

// Round 4
// 264.997 us; speedup vs baseline: 2.7435x; 1.3094x over previous
//
#include <hip/hip_runtime.h>
#include <math.h>

#define B_ 64
#define I_ 4096
#define P_ 8      // Din
#define N_ 10
#define D_ 16
#define ND_ 160   // N*D
#define BND_ (B_*ND_)   // 10240
#define EPS_ 1e-7f

#define IPB_ 8                 // i per block
#define NBLK_ (I_ / IPB_)      // 512 blocks = exactly 2 blocks/CU on 256 CUs
#define WTILE_ (N_ * P_ * D_)  // 1280 floats of W per i (global, unpadded)
#define NSTR_ 144              // padded n-stride in LDS (floats)
#define ILSTR_ (N_ * NSTR_)    // 1440 floats per i in LDS
#define RBLK_ 320              // blocks participating in the distributed reduce

// DPP cross-lane value fetch on the VALU pipe (no DS traffic).
template<int CTRL>
__device__ __forceinline__ float dpp_bcast(float v) {
    int r = __builtin_amdgcn_update_dpp(0, __float_as_int(v), CTRL, 0xF, 0xF, true);
    return __int_as_float(r);
}

// ---- agent-scope (sc1) accessors: route cross-block data via the device-
// coherent point, bypassing the non-coherent per-XCD L2s. All cross-block
// data (part, Vc, cnt) moves ONLY through these.
__device__ __forceinline__ void agent_store_f2(float* dst, float a, float b) {
    float2 v; v.x = a; v.y = b;
    unsigned long long u; __builtin_memcpy(&u, &v, 8);
    __hip_atomic_store((unsigned long long*)dst, u,
                       __ATOMIC_RELAXED, __HIP_MEMORY_SCOPE_AGENT);
}
__device__ __forceinline__ float2 agent_load_f2(const float* src) {
    unsigned long long u = __hip_atomic_load((unsigned long long*)src,
                       __ATOMIC_RELAXED, __HIP_MEMORY_SCOPE_AGENT);
    float2 v; __builtin_memcpy(&v, &u, 8); return v;
}
__device__ __forceinline__ float agent_load_f(const float* src) {
    return __hip_atomic_load((float*)src, __ATOMIC_RELAXED,
                             __HIP_MEMORY_SCOPE_AGENT);
}
__device__ __forceinline__ void agent_store_f(float* dst, float v) {
    __hip_atomic_store(dst, v, __ATOMIC_RELAXED, __HIP_MEMORY_SCOPE_AGENT);
}

// R16 grid barrier: FULLY RELAXED atomics -- zero cache-maintenance ops.
// (R15 post-mortem: the ACQ_REL fetch_add's acquire half emits buffer_inv on
// gfx950 -> 512 L2 flash-invalidates per barrier + x/W refetch storms = the
// ~250 us stall. FETCH_SIZE 78 MB confirmed the refetch.)
// Correctness without maintenance:
//  - release: __syncthreads() makes every wave drain vmcnt(0), so all sc1
//    stores are acked at the device-coherent point BEFORE thread 0's add.
//  - acquire: readers touch part/Vc only via sc1 loads, which always fetch
//    from the coherent point -- no stale-L2 risk by construction.
//  - workgroup-scope fences (s_waitcnt only, never buffer_inv/wbl2) pin the
//    COMPILER from hoisting post-barrier loads above the spin.
// Monotonic target (any initial counter value / rocprof replay safe);
// ~20 ms timeout breaks visibly instead of hanging.
__device__ __forceinline__ void gridbar(unsigned* cnt, int slot) {
    __syncthreads();                       // all waves: vmcnt(0) drained
    if (threadIdx.x == 0) {
        __builtin_amdgcn_fence(__ATOMIC_RELEASE, "workgroup");   // compiler pin
        unsigned old = __hip_atomic_fetch_add(&cnt[slot], 1u,
                            __ATOMIC_RELAXED, __HIP_MEMORY_SCOPE_AGENT);
        unsigned tgt = (old / (unsigned)NBLK_ + 1u) * (unsigned)NBLK_;
        long long t0 = (long long)__builtin_amdgcn_s_memrealtime();
        while (__hip_atomic_load(&cnt[slot], __ATOMIC_RELAXED,
                                 __HIP_MEMORY_SCOPE_AGENT) < tgt) {
            __builtin_amdgcn_s_sleep(8);
            if ((long long)__builtin_amdgcn_s_memrealtime() - t0 > 2000000LL)
                break;                     // ~20 ms @ 100 MHz: fail, don't hang
        }
        __builtin_amdgcn_fence(__ATOMIC_ACQUIRE, "workgroup");   // compiler pin
    }
    __syncthreads();
}

// __launch_bounds__(256, 2) -- R2-proven AND required for barrier safety
// (512 blocks = 2/CU x 256 CU all co-resident; LDS 46KB x2 <= 160KB).
// NOT hipLaunchCooperativeKernel (R11: deadlocked under graph capture).
__global__ __launch_bounds__(256, 2)
void digitcaps_fused(const float* __restrict__ x, const float* __restrict__ W,
                     float* __restrict__ part, float* __restrict__ Vc,
                     float* __restrict__ out, unsigned* __restrict__ cnt)
{
    __shared__ float wsh[IPB_ * ILSTR_];   // 46080 B
    __shared__ float rsm[4][32];
    const int t = threadIdx.x;
    const int lane = t & 63;
    const int ds  = lane & 7;              // d-pair index: d = 2ds, 2ds+1
    const int np  = (lane >> 3) & 1;       // n-parity (owns n = np+2k)
    const int bl2 = lane >> 4;             // 0..3
    const int wv  = t >> 6;                // 0..3
    const int bb  = wv * 16 + bl2 * 4;     // first of this thread's 4 b's
    const int i0  = blockIdx.x * IPB_;

    // ---- stage W[i0..i0+8) into padded LDS ONCE: 10 float4/thread ----
    {
        const float4* __restrict__ Wg = (const float4*)(W + (size_t)i0 * WTILE_);
        float4* __restrict__ Ws = (float4*)wsh;
#pragma unroll
        for (int c0 = 0; c0 < (IPB_ * WTILE_) / (4 * 256); ++c0) {  // 10
            int c  = c0 * 256 + t;
            int il = c / 320;
            int r  = c - il * 320;
            int n  = r >> 5;
            int s  = r & 31;
            Ws[il * 360 + n * 36 + s] = Wg[c];
        }
    }
    __syncthreads();   // W staged

    float vprev = 0.f;   // reducer-thread register copy of Vc[o2] (same
                         // thread owns the same output every iteration)

    for (int it = 0; it < 3; ++it) {
        const bool uni = (it == 0);

        float vc[4][5][2];
        if (!uni) {
#pragma unroll
            for (int j = 0; j < 4; ++j)
#pragma unroll
                for (int k = 0; k < 5; ++k) {
                    float2 v = agent_load_f2(Vc + (size_t)(bb + j) * ND_
                                             + (np + 2 * k) * D_ + 2 * ds);
                    vc[j][k][0] = v.x; vc[j][k][1] = v.y;
                }
        }

        float acc[4][5][2];
#pragma unroll
        for (int j = 0; j < 4; ++j)
#pragma unroll
            for (int k = 0; k < 5; ++k) { acc[j][k][0] = 0.f; acc[j][k][1] = 0.f; }

        // preload x for il=0 (stays L2-hot now: no more invalidates)
        float xv[4][P_];
#pragma unroll
        for (int j = 0; j < 4; ++j) {
            const float4* xp = (const float4*)(x + ((size_t)(bb + j) * I_ + i0) * P_);
            float4 a0 = xp[0], a1 = xp[1];
            xv[j][0]=a0.x; xv[j][1]=a0.y; xv[j][2]=a0.z; xv[j][3]=a0.w;
            xv[j][4]=a1.x; xv[j][5]=a1.y; xv[j][6]=a1.z; xv[j][7]=a1.w;
        }

#pragma unroll 1
        for (int il = 0; il < IPB_; ++il) {
            const float* __restrict__ Wb = wsh + il * ILSTR_ + np * NSTR_ + 2 * ds;

            // u_hat fragments tv[j][k][d]: 40 ds_read_b64, 320 FMA
            float tv[4][5][2];
#pragma unroll
            for (int k = 0; k < 5; ++k) {
#pragma unroll
                for (int j = 0; j < 4; ++j) { tv[j][k][0] = 0.f; tv[j][k][1] = 0.f; }
#pragma unroll
                for (int p = 0; p < P_; ++p) {
                    float2 w = *(const float2*)(Wb + k * 2 * NSTR_ + p * D_);
#pragma unroll
                    for (int j = 0; j < 4; ++j) {
                        tv[j][k][0] = fmaf(w.x, xv[j][p], tv[j][k][0]);
                        tv[j][k][1] = fmaf(w.y, xv[j][p], tv[j][k][1]);
                    }
                }
            }

            // prefetch x for il+1
            float xn[4][P_];
            if (il + 1 < IPB_) {
#pragma unroll
                for (int j = 0; j < 4; ++j) {
                    const float4* xp = (const float4*)(x + ((size_t)(bb + j) * I_
                                                            + i0 + il + 1) * P_);
                    float4 a0 = xp[0], a1 = xp[1];
                    xn[j][0]=a0.x; xn[j][1]=a0.y; xn[j][2]=a0.z; xn[j][3]=a0.w;
                    xn[j][4]=a1.x; xn[j][5]=a1.y; xn[j][6]=a1.z; xn[j][7]=a1.w;
                }
            }

            if (uni) {
#pragma unroll
                for (int j = 0; j < 4; ++j)
#pragma unroll
                    for (int k = 0; k < 5; ++k) {
                        acc[j][k][0] += tv[j][k][0];
                        acc[j][k][1] += tv[j][k][1];
                    }
            } else {
#pragma unroll
                for (int j = 0; j < 4; ++j) {
                    float e[5];
                    float m = -1e30f;
#pragma unroll
                    for (int k = 0; k < 5; ++k) {
                        float l = fmaf(tv[j][k][1], vc[j][k][1],
                                       tv[j][k][0] * vc[j][k][0]);
                        l += dpp_bcast<0xB1>(l);
                        l += dpp_bcast<0x4E>(l);
                        l += dpp_bcast<0x141>(l);   // full d-dot across 8 ds lanes
                        e[k] = l;
                        m = fmaxf(m, l);
                    }
                    m = fmaxf(m, dpp_bcast<0x140>(m));   // max over other parity
                    float se = 0.f;
#pragma unroll
                    for (int k = 0; k < 5; ++k) { e[k] = __expf(e[k] - m); se += e[k]; }
                    se += dpp_bcast<0x140>(se);
                    float inv = 1.f / se;
#pragma unroll
                    for (int k = 0; k < 5; ++k) {
                        float cn = e[k] * inv;
                        acc[j][k][0] = fmaf(cn, tv[j][k][0], acc[j][k][0]);
                        acc[j][k][1] = fmaf(cn, tv[j][k][1], acc[j][k][1]);
                    }
                }
            }

            if (il + 1 < IPB_) {
#pragma unroll
                for (int j = 0; j < 4; ++j)
#pragma unroll
                    for (int p = 0; p < P_; ++p) xv[j][p] = xn[j][p];
            }
        }

        // store partials via sc1 (device-coherent), NATURAL layout
#pragma unroll
        for (int j = 0; j < 4; ++j) {
            float* __restrict__ dst = part + (size_t)blockIdx.x * BND_
                                      + (size_t)(bb + j) * ND_ + np * D_ + 2 * ds;
#pragma unroll
            for (int k = 0; k < 5; ++k)
                agent_store_f2(dst + k * 2 * D_, acc[j][k][0], acc[j][k][1]);
        }

        gridbar(cnt, it * 2);   // all partials visible (sc1-acked)

        // ---- distributed reduce: blocks 0..319, 32 outputs each ----
        if (blockIdx.x < RBLK_) {
            const int oi = t & 31;
            const int tp = t >> 5;             // 0..7, 64 rows each
            const int o  = blockIdx.x * 32 + oi;
            float s = 0.f;
            const float* __restrict__ p0 = part + (size_t)(tp * 64) * BND_ + o;
#pragma unroll 8
            for (int j = 0; j < 64; ++j)
                s += agent_load_f(p0 + (size_t)j * BND_);
            s += __shfl_down(s, 32);           // tp pairs within wave
            if ((t & 63) < 32) rsm[t >> 6][oi] = s;
            __syncthreads();
            if (t < 32) {
                float tot = (rsm[0][t] + rsm[1][t]) + (rsm[2][t] + rsm[3][t]);
                tot *= uni ? 0.1f : 1.0f;
                float sq = tot * tot;
                float v = tot * (sq / ((1.f + sq) * sqrtf(sq + EPS_)));
                int o2 = blockIdx.x * 32 + t;
                if (it == 0)      { vprev = v;      agent_store_f(Vc + o2, vprev); }
                else if (it == 1) { vprev += v;     agent_store_f(Vc + o2, vprev); }
                else              out[o2] = v;     // normal store: kernel-end
            }                                      // writeback covers host read
        }

        if (it < 2) gridbar(cnt, it * 2 + 1);  // Vc visible to next pass
    }
}

extern "C" void kernel_launch(void* const* d_in, const int* in_sizes, int n_in,
                              void* d_out, int out_size, void* d_ws, size_t ws_size,
                              hipStream_t stream)
{
    const float* x = (const float*)d_in[0];   // [64, 4096, 8] f32
    const float* W = (const float*)d_in[1];   // [4096, 10, 8, 16] f32
    float* out = (float*)d_out;               // [64, 10, 1, 16] f32

    // ws: part (512*10240 f = 21 MB) | Vc (10240 f) | cnt (8 u32)
    float* part = (float*)d_ws;
    float* Vc   = part + (size_t)NBLK_ * BND_;
    unsigned* cnt = (unsigned*)(Vc + BND_);

    // zero barrier counters (graph-capturable; barrier is monotonic so a
    // replay that skips this node is still correct)
    hipMemsetAsync(cnt, 0, 8 * sizeof(unsigned), stream);

    digitcaps_fused<<<dim3(NBLK_), dim3(256), 0, stream>>>(x, W, part, Vc, out, cnt);
}

// Round 5
// 176.270 us; speedup vs baseline: 4.1245x; 1.5034x over previous
//
#include <hip/hip_runtime.h>
#include <math.h>

#define B_ 64
#define I_ 4096
#define P_ 8      // Din
#define N_ 10
#define D_ 16
#define ND_ 160   // N*D
#define BND_ (B_*ND_)   // 10240
#define EPS_ 1e-7f

#define IPB_ 8                 // i per block
#define NBLK_ (I_ / IPB_)      // 512 blocks = exactly 2 blocks/CU on 256 CUs
#define WTILE_ (N_ * P_ * D_)  // 1280 floats of W per i (global, unpadded)
#define NSTR_ 144              // padded n-stride in LDS (floats)
#define ILSTR_ (N_ * NSTR_)    // 1440 floats per i in LDS
#define RBLK_ 320              // blocks participating in the distributed reduce

// tree-barrier geometry: 16 groups x 32 blocks; each counter on its own 64 B line
#define NGRP_ 16
#define GSZ_  32
#define LINEW_ 16              // uints per 64 B line
#define SLOTW_ ((NGRP_ + 1) * LINEW_)   // 17 lines per barrier slot
#define NSLOT_ 5

// DPP cross-lane value fetch on the VALU pipe (no DS traffic).
template<int CTRL>
__device__ __forceinline__ float dpp_bcast(float v) {
    int r = __builtin_amdgcn_update_dpp(0, __float_as_int(v), CTRL, 0xF, 0xF, true);
    return __int_as_float(r);
}

// ---- agent-scope (sc1) accessors: route cross-block data via the device-
// coherent point, bypassing the non-coherent per-XCD L2s. All cross-block
// data (part, Vc, cnt) moves ONLY through these.
__device__ __forceinline__ void agent_store_f2(float* dst, float a, float b) {
    float2 v; v.x = a; v.y = b;
    unsigned long long u; __builtin_memcpy(&u, &v, 8);
    __hip_atomic_store((unsigned long long*)dst, u,
                       __ATOMIC_RELAXED, __HIP_MEMORY_SCOPE_AGENT);
}
__device__ __forceinline__ float2 agent_load_f2(const float* src) {
    unsigned long long u = __hip_atomic_load((unsigned long long*)src,
                       __ATOMIC_RELAXED, __HIP_MEMORY_SCOPE_AGENT);
    float2 v; __builtin_memcpy(&v, &u, 8); return v;
}
__device__ __forceinline__ float agent_load_f(const float* src) {
    return __hip_atomic_load((float*)src, __ATOMIC_RELAXED,
                             __HIP_MEMORY_SCOPE_AGENT);
}
__device__ __forceinline__ void agent_store_f(float* dst, float v) {
    __hip_atomic_store(dst, v, __ATOMIC_RELAXED, __HIP_MEMORY_SCOPE_AGENT);
}

// R17 TREE grid barrier (R16 post-mortem: single-line barrier = 512 RMWs +
// 512 spin-pollers on ONE IF$ line -> poll storm starves the arrival RMWs,
// ~30 us/barrier convoy. Fix: spread arrivals over 16 lines, poll fan-out
// through per-group 'go' words; max same-line traffic ~32 RMWs + ~52 polls/us).
//  - arrive: fetch_add on group line (g = blockIdx&15 so temporally-adjacent
//    blocks hit different lines); 32nd arrival of a group RMWs the root.
//  - release: 16 leader blocks (blockIdx<16) poll root; on completion store
//    go=epoch+1 to their group line; members poll their group's go word.
//  - All relaxed sc1 atomics, zero cache-maintenance (R15/R16 lesson).
//    Ordering: __syncthreads drains vmcnt(0) (all sc1 stores acked at the
//    coherent point) before arrival; post-barrier loads are data-dependent
//    on the go/root load; workgroup fences pin the compiler only.
//  - Epoch math needs consistent initial counters -> memset stays (poison
//    is not guaranteed zero). ~20 ms timeouts break visibly, never hang.
__device__ __forceinline__ void gridbar(unsigned* cnt, int slot) {
    __syncthreads();                       // all waves: vmcnt(0) drained
    if (threadIdx.x == 0) {
        unsigned* base = cnt + slot * SLOTW_;
        const unsigned g = (unsigned)blockIdx.x & (NGRP_ - 1u);
        unsigned* gl = base + g * LINEW_;          // [0]=arrive ctr, [1]=go
        unsigned* rp = base + NGRP_ * LINEW_;      // root line [0]
        __builtin_amdgcn_fence(__ATOMIC_RELEASE, "workgroup");   // compiler pin
        unsigned gold = __hip_atomic_fetch_add(&gl[0], 1u,
                            __ATOMIC_RELAXED, __HIP_MEMORY_SCOPE_AGENT);
        unsigned epoch = gold / (unsigned)GSZ_;
        if ((gold % (unsigned)GSZ_) == (unsigned)GSZ_ - 1u)   // group complete
            __hip_atomic_fetch_add(&rp[0], 1u,
                __ATOMIC_RELAXED, __HIP_MEMORY_SCOPE_AGENT);
        long long t0 = (long long)__builtin_amdgcn_s_memrealtime();
        if ((unsigned)blockIdx.x < (unsigned)NGRP_) {   // leader of group g
            unsigned rtgt = (epoch + 1u) * (unsigned)NGRP_;
            while (__hip_atomic_load(&rp[0], __ATOMIC_RELAXED,
                                     __HIP_MEMORY_SCOPE_AGENT) < rtgt) {
                __builtin_amdgcn_s_sleep(8);
                if ((long long)__builtin_amdgcn_s_memrealtime() - t0 > 2000000LL)
                    break;                 // ~20 ms: fail visibly, don't hang
            }
            __hip_atomic_store(&gl[1], epoch + 1u,
                __ATOMIC_RELAXED, __HIP_MEMORY_SCOPE_AGENT);
        }
        while (__hip_atomic_load(&gl[1], __ATOMIC_RELAXED,
                                 __HIP_MEMORY_SCOPE_AGENT) < epoch + 1u) {
            __builtin_amdgcn_s_sleep(8);
            if ((long long)__builtin_amdgcn_s_memrealtime() - t0 > 2000000LL)
                break;
        }
        __builtin_amdgcn_fence(__ATOMIC_ACQUIRE, "workgroup");   // compiler pin
    }
    __syncthreads();
}

// __launch_bounds__(256, 2) -- R2-proven AND required for barrier safety
// (512 blocks = 2/CU x 256 CU all co-resident; LDS 46KB x2 <= 160KB).
// NOT hipLaunchCooperativeKernel (R11: deadlocked under graph capture).
__global__ __launch_bounds__(256, 2)
void digitcaps_fused(const float* __restrict__ x, const float* __restrict__ W,
                     float* __restrict__ part, float* __restrict__ Vc,
                     float* __restrict__ out, unsigned* __restrict__ cnt)
{
    __shared__ float wsh[IPB_ * ILSTR_];   // 46080 B
    __shared__ float rsm[4][32];
    const int t = threadIdx.x;
    const int lane = t & 63;
    const int ds  = lane & 7;              // d-pair index: d = 2ds, 2ds+1
    const int np  = (lane >> 3) & 1;       // n-parity (owns n = np+2k)
    const int bl2 = lane >> 4;             // 0..3
    const int wv  = t >> 6;                // 0..3
    const int bb  = wv * 16 + bl2 * 4;     // first of this thread's 4 b's
    const int i0  = blockIdx.x * IPB_;

    // ---- stage W[i0..i0+8) into padded LDS ONCE: 10 float4/thread ----
    {
        const float4* __restrict__ Wg = (const float4*)(W + (size_t)i0 * WTILE_);
        float4* __restrict__ Ws = (float4*)wsh;
#pragma unroll
        for (int c0 = 0; c0 < (IPB_ * WTILE_) / (4 * 256); ++c0) {  // 10
            int c  = c0 * 256 + t;
            int il = c / 320;
            int r  = c - il * 320;
            int n  = r >> 5;
            int s  = r & 31;
            Ws[il * 360 + n * 36 + s] = Wg[c];
        }
    }
    __syncthreads();   // W staged

    float vprev = 0.f;   // reducer-thread register copy of Vc[o2] (same
                         // thread owns the same output every iteration)

    for (int it = 0; it < 3; ++it) {
        const bool uni = (it == 0);

        float vc[4][5][2];
        if (!uni) {
#pragma unroll
            for (int j = 0; j < 4; ++j)
#pragma unroll
                for (int k = 0; k < 5; ++k) {
                    float2 v = agent_load_f2(Vc + (size_t)(bb + j) * ND_
                                             + (np + 2 * k) * D_ + 2 * ds);
                    vc[j][k][0] = v.x; vc[j][k][1] = v.y;
                }
        }

        float acc[4][5][2];
#pragma unroll
        for (int j = 0; j < 4; ++j)
#pragma unroll
            for (int k = 0; k < 5; ++k) { acc[j][k][0] = 0.f; acc[j][k][1] = 0.f; }

        // preload x for il=0
        float xv[4][P_];
#pragma unroll
        for (int j = 0; j < 4; ++j) {
            const float4* xp = (const float4*)(x + ((size_t)(bb + j) * I_ + i0) * P_);
            float4 a0 = xp[0], a1 = xp[1];
            xv[j][0]=a0.x; xv[j][1]=a0.y; xv[j][2]=a0.z; xv[j][3]=a0.w;
            xv[j][4]=a1.x; xv[j][5]=a1.y; xv[j][6]=a1.z; xv[j][7]=a1.w;
        }

#pragma unroll 1
        for (int il = 0; il < IPB_; ++il) {
            const float* __restrict__ Wb = wsh + il * ILSTR_ + np * NSTR_ + 2 * ds;

            // u_hat fragments tv[j][k][d]: 40 ds_read_b64, 320 FMA
            float tv[4][5][2];
#pragma unroll
            for (int k = 0; k < 5; ++k) {
#pragma unroll
                for (int j = 0; j < 4; ++j) { tv[j][k][0] = 0.f; tv[j][k][1] = 0.f; }
#pragma unroll
                for (int p = 0; p < P_; ++p) {
                    float2 w = *(const float2*)(Wb + k * 2 * NSTR_ + p * D_);
#pragma unroll
                    for (int j = 0; j < 4; ++j) {
                        tv[j][k][0] = fmaf(w.x, xv[j][p], tv[j][k][0]);
                        tv[j][k][1] = fmaf(w.y, xv[j][p], tv[j][k][1]);
                    }
                }
            }

            // prefetch x for il+1
            float xn[4][P_];
            if (il + 1 < IPB_) {
#pragma unroll
                for (int j = 0; j < 4; ++j) {
                    const float4* xp = (const float4*)(x + ((size_t)(bb + j) * I_
                                                            + i0 + il + 1) * P_);
                    float4 a0 = xp[0], a1 = xp[1];
                    xn[j][0]=a0.x; xn[j][1]=a0.y; xn[j][2]=a0.z; xn[j][3]=a0.w;
                    xn[j][4]=a1.x; xn[j][5]=a1.y; xn[j][6]=a1.z; xn[j][7]=a1.w;
                }
            }

            if (uni) {
#pragma unroll
                for (int j = 0; j < 4; ++j)
#pragma unroll
                    for (int k = 0; k < 5; ++k) {
                        acc[j][k][0] += tv[j][k][0];
                        acc[j][k][1] += tv[j][k][1];
                    }
            } else {
#pragma unroll
                for (int j = 0; j < 4; ++j) {
                    float e[5];
                    float m = -1e30f;
#pragma unroll
                    for (int k = 0; k < 5; ++k) {
                        float l = fmaf(tv[j][k][1], vc[j][k][1],
                                       tv[j][k][0] * vc[j][k][0]);
                        l += dpp_bcast<0xB1>(l);
                        l += dpp_bcast<0x4E>(l);
                        l += dpp_bcast<0x141>(l);   // full d-dot across 8 ds lanes
                        e[k] = l;
                        m = fmaxf(m, l);
                    }
                    m = fmaxf(m, dpp_bcast<0x140>(m));   // max over other parity
                    float se = 0.f;
#pragma unroll
                    for (int k = 0; k < 5; ++k) { e[k] = __expf(e[k] - m); se += e[k]; }
                    se += dpp_bcast<0x140>(se);
                    float inv = 1.f / se;
#pragma unroll
                    for (int k = 0; k < 5; ++k) {
                        float cn = e[k] * inv;
                        acc[j][k][0] = fmaf(cn, tv[j][k][0], acc[j][k][0]);
                        acc[j][k][1] = fmaf(cn, tv[j][k][1], acc[j][k][1]);
                    }
                }
            }

            if (il + 1 < IPB_) {
#pragma unroll
                for (int j = 0; j < 4; ++j)
#pragma unroll
                    for (int p = 0; p < P_; ++p) xv[j][p] = xn[j][p];
            }
        }

        // store partials via sc1 (device-coherent), NATURAL layout
#pragma unroll
        for (int j = 0; j < 4; ++j) {
            float* __restrict__ dst = part + (size_t)blockIdx.x * BND_
                                      + (size_t)(bb + j) * ND_ + np * D_ + 2 * ds;
#pragma unroll
            for (int k = 0; k < 5; ++k)
                agent_store_f2(dst + k * 2 * D_, acc[j][k][0], acc[j][k][1]);
        }

        gridbar(cnt, it * 2);   // all partials visible (sc1-acked)

        // ---- distributed reduce: blocks 0..319, 32 outputs each ----
        if (blockIdx.x < RBLK_) {
            const int oi = t & 31;
            const int tp = t >> 5;             // 0..7, 64 rows each
            const int o  = blockIdx.x * 32 + oi;
            float s = 0.f;
            const float* __restrict__ p0 = part + (size_t)(tp * 64) * BND_ + o;
#pragma unroll 8
            for (int j = 0; j < 64; ++j)
                s += agent_load_f(p0 + (size_t)j * BND_);
            s += __shfl_down(s, 32);           // tp pairs within wave
            if ((t & 63) < 32) rsm[t >> 6][oi] = s;
            __syncthreads();
            if (t < 32) {
                float tot = (rsm[0][t] + rsm[1][t]) + (rsm[2][t] + rsm[3][t]);
                tot *= uni ? 0.1f : 1.0f;
                float sq = tot * tot;
                float v = tot * (sq / ((1.f + sq) * sqrtf(sq + EPS_)));
                int o2 = blockIdx.x * 32 + t;
                if (it == 0)      { vprev = v;      agent_store_f(Vc + o2, vprev); }
                else if (it == 1) { vprev += v;     agent_store_f(Vc + o2, vprev); }
                else              out[o2] = v;     // normal store: kernel-end
            }                                      // writeback covers host read
        }

        if (it < 2) gridbar(cnt, it * 2 + 1);  // Vc visible to next pass
    }
}

extern "C" void kernel_launch(void* const* d_in, const int* in_sizes, int n_in,
                              void* d_out, int out_size, void* d_ws, size_t ws_size,
                              hipStream_t stream)
{
    const float* x = (const float*)d_in[0];   // [64, 4096, 8] f32
    const float* W = (const float*)d_in[1];   // [4096, 10, 8, 16] f32
    float* out = (float*)d_out;               // [64, 10, 1, 16] f32

    // ws: part (512*10240 f = 21 MB) | Vc (10240 f) | cnt (5 slots x 17 lines)
    float* part = (float*)d_ws;
    float* Vc   = part + (size_t)NBLK_ * BND_;
    unsigned* cnt = (unsigned*)(Vc + BND_);

    // zero barrier counters (tree epoch math needs consistent init; poison
    // is not guaranteed zero). Graph-capturable async memset.
    hipMemsetAsync(cnt, 0, NSLOT_ * SLOTW_ * sizeof(unsigned), stream);

    digitcaps_fused<<<dim3(NBLK_), dim3(256), 0, stream>>>(x, W, part, Vc, out, cnt);
}

// Round 6
// 169.866 us; speedup vs baseline: 4.2800x; 1.0377x over previous
//
#include <hip/hip_runtime.h>
#include <math.h>

#define B_ 64
#define I_ 4096
#define P_ 8      // Din
#define N_ 10
#define D_ 16
#define ND_ 160   // N*D
#define BND_ (B_*ND_)   // 10240
#define EPS_ 1e-7f

#define IPB_ 8                 // i per block
#define NBLK_ (I_ / IPB_)      // 512 blocks = exactly 2 blocks/CU on 256 CUs
#define WTILE_ (N_ * P_ * D_)  // 1280 floats of W per i (global, unpadded)
#define NSTR_ 144              // padded n-stride in LDS (floats)
#define ILSTR_ (N_ * NSTR_)    // 1440 floats per i in LDS
#define XSTR_ 68               // x row stride in LDS (floats): 16B-aligned, <=2-way

// tree-barrier geometry: 16 groups x 32 blocks; each counter on its own 64 B line
#define NGRP_ 16
#define GSZ_  32
#define LINEW_ 16              // uints per 64 B line
#define SLOTW_ ((NGRP_ + 1) * LINEW_)   // 17 lines per barrier slot
#define NSLOT_ 5

// DPP cross-lane value fetch on the VALU pipe (no DS traffic).
template<int CTRL>
__device__ __forceinline__ float dpp_bcast(float v) {
    int r = __builtin_amdgcn_update_dpp(0, __float_as_int(v), CTRL, 0xF, 0xF, true);
    return __int_as_float(r);
}

// ---- agent-scope (sc1) accessors: route cross-block data via the device-
// coherent point, bypassing the non-coherent per-XCD L2s. All cross-block
// data (part, Vc, cnt) moves ONLY through these.
__device__ __forceinline__ void agent_store_f2(float* dst, float a, float b) {
    float2 v; v.x = a; v.y = b;
    unsigned long long u; __builtin_memcpy(&u, &v, 8);
    __hip_atomic_store((unsigned long long*)dst, u,
                       __ATOMIC_RELAXED, __HIP_MEMORY_SCOPE_AGENT);
}
__device__ __forceinline__ float2 agent_load_f2(const float* src) {
    unsigned long long u = __hip_atomic_load((unsigned long long*)src,
                       __ATOMIC_RELAXED, __HIP_MEMORY_SCOPE_AGENT);
    float2 v; __builtin_memcpy(&v, &u, 8); return v;
}
__device__ __forceinline__ void agent_store_f(float* dst, float v) {
    __hip_atomic_store(dst, v, __ATOMIC_RELAXED, __HIP_MEMORY_SCOPE_AGENT);
}

// R17 tree grid barrier (proven: 211->115 us). R18: s_sleep(8)->(1) to cut
// detection latency (~0.5 us/hop -> ~0.2). Poll rates stay trivial per line
// (31 members or 16 leaders per 64 B line).
//  - All relaxed sc1 atomics, zero cache-maintenance (R15/R16 lesson:
//    ACQ_REL's buffer_inv cost ~16 us/barrier).
//  - Ordering: __syncthreads drains vmcnt(0) (all sc1 stores acked at the
//    coherent point) before arrival; post-barrier reads are sc1 loads.
//  - ~20 ms timeouts break visibly, never hang.
__device__ __forceinline__ void gridbar(unsigned* cnt, int slot) {
    __syncthreads();                       // all waves: vmcnt(0) drained
    if (threadIdx.x == 0) {
        unsigned* base = cnt + slot * SLOTW_;
        const unsigned g = (unsigned)blockIdx.x & (NGRP_ - 1u);
        unsigned* gl = base + g * LINEW_;          // [0]=arrive ctr, [1]=go
        unsigned* rp = base + NGRP_ * LINEW_;      // root line [0]
        __builtin_amdgcn_fence(__ATOMIC_RELEASE, "workgroup");   // compiler pin
        unsigned gold = __hip_atomic_fetch_add(&gl[0], 1u,
                            __ATOMIC_RELAXED, __HIP_MEMORY_SCOPE_AGENT);
        unsigned epoch = gold / (unsigned)GSZ_;
        if ((gold % (unsigned)GSZ_) == (unsigned)GSZ_ - 1u)   // group complete
            __hip_atomic_fetch_add(&rp[0], 1u,
                __ATOMIC_RELAXED, __HIP_MEMORY_SCOPE_AGENT);
        long long t0 = (long long)__builtin_amdgcn_s_memrealtime();
        if ((unsigned)blockIdx.x < (unsigned)NGRP_) {   // leader of group g
            unsigned rtgt = (epoch + 1u) * (unsigned)NGRP_;
            while (__hip_atomic_load(&rp[0], __ATOMIC_RELAXED,
                                     __HIP_MEMORY_SCOPE_AGENT) < rtgt) {
                __builtin_amdgcn_s_sleep(1);
                if ((long long)__builtin_amdgcn_s_memrealtime() - t0 > 2000000LL)
                    break;                 // ~20 ms: fail visibly, don't hang
            }
            __hip_atomic_store(&gl[1], epoch + 1u,
                __ATOMIC_RELAXED, __HIP_MEMORY_SCOPE_AGENT);
        } else {
            while (__hip_atomic_load(&gl[1], __ATOMIC_RELAXED,
                                     __HIP_MEMORY_SCOPE_AGENT) < epoch + 1u) {
                __builtin_amdgcn_s_sleep(1);
                if ((long long)__builtin_amdgcn_s_memrealtime() - t0 > 2000000LL)
                    break;
            }
        }
        __builtin_amdgcn_fence(__ATOMIC_ACQUIRE, "workgroup");   // compiler pin
    }
    __syncthreads();
}

// __launch_bounds__(256, 2) -- R2-proven AND required for barrier safety
// (512 blocks = 2/CU x 256 CU all co-resident; LDS 67.3KB x2 <= 160KB).
// NOT hipLaunchCooperativeKernel (R11: deadlocked under graph capture).
__global__ __launch_bounds__(256, 2)
void digitcaps_fused(const float* __restrict__ x, const float* __restrict__ W,
                     float* __restrict__ part, float* __restrict__ Vc,
                     float* __restrict__ out, unsigned* __restrict__ cnt)
{
    __shared__ float wsh[IPB_ * ILSTR_];   // 46080 B
    __shared__ float xsh[B_ * XSTR_];      // 17408 B: x[b][il*8+p], stride 68
    __shared__ float4 rsm4[48][5];         // 3840 B reduce combine
    const int t = threadIdx.x;
    const int lane = t & 63;
    const int ds  = lane & 7;              // d-pair index: d = 2ds, 2ds+1
    const int np  = (lane >> 3) & 1;       // n-parity (owns n = np+2k)
    const int bl2 = lane >> 4;             // 0..3
    const int wv  = t >> 6;                // 0..3
    const int bb  = wv * 16 + bl2 * 4;     // first of this thread's 4 b's
    const int i0  = blockIdx.x * IPB_;

    // ---- stage W[i0..i0+8) into padded LDS ONCE: 10 float4/thread ----
    {
        const float4* __restrict__ Wg = (const float4*)(W + (size_t)i0 * WTILE_);
        float4* __restrict__ Ws = (float4*)wsh;
#pragma unroll
        for (int c0 = 0; c0 < (IPB_ * WTILE_) / (4 * 256); ++c0) {  // 10
            int c  = c0 * 256 + t;
            int il = c / 320;
            int r  = c - il * 320;
            int n  = r >> 5;
            int s  = r & 31;
            Ws[il * 360 + n * 36 + s] = Wg[c];
        }
    }
    // ---- stage x[b][i0..i0+8][:] into LDS ONCE (R18: was re-read from
    // global 16x-redundantly per il per pass; now 8.4 MB read once total) ----
    {
        const int xb = t >> 2;             // b 0..63
        const int xc = t & 3;
        const float4* __restrict__ xg = (const float4*)(x + ((size_t)xb * I_ + i0) * P_);
        float4* __restrict__ xd = (float4*)(xsh + xb * XSTR_);
#pragma unroll
        for (int q = 0; q < 4; ++q)
            xd[xc * 4 + q] = xg[xc * 4 + q];
    }
    __syncthreads();   // W + x staged

    float vprev = 0.f;   // owner-thread (t<20) register copy of Vc[o0+t]

    for (int it = 0; it < 3; ++it) {
        const bool uni = (it == 0);

        float vc[4][5][2];
        if (!uni) {
#pragma unroll
            for (int j = 0; j < 4; ++j)
#pragma unroll
                for (int k = 0; k < 5; ++k) {
                    float2 v = agent_load_f2(Vc + (size_t)(bb + j) * ND_
                                             + (np + 2 * k) * D_ + 2 * ds);
                    vc[j][k][0] = v.x; vc[j][k][1] = v.y;
                }
        }

        float acc[4][5][2];
#pragma unroll
        for (int j = 0; j < 4; ++j)
#pragma unroll
            for (int k = 0; k < 5; ++k) { acc[j][k][0] = 0.f; acc[j][k][1] = 0.f; }

#pragma unroll 1
        for (int il = 0; il < IPB_; ++il) {
            const float* __restrict__ Wb = wsh + il * ILSTR_ + np * NSTR_ + 2 * ds;

            // x fragments from LDS (16-lane broadcast, 2x b128/j)
            float xr[4][P_];
#pragma unroll
            for (int j = 0; j < 4; ++j) {
                const float4* xp = (const float4*)(xsh + (bb + j) * XSTR_ + il * P_);
                float4 a0 = xp[0], a1 = xp[1];
                xr[j][0]=a0.x; xr[j][1]=a0.y; xr[j][2]=a0.z; xr[j][3]=a0.w;
                xr[j][4]=a1.x; xr[j][5]=a1.y; xr[j][6]=a1.z; xr[j][7]=a1.w;
            }

            // u_hat fragments tv[j][k][d]: 40 ds_read_b64, 320 FMA
            float tv[4][5][2];
#pragma unroll
            for (int k = 0; k < 5; ++k) {
#pragma unroll
                for (int j = 0; j < 4; ++j) { tv[j][k][0] = 0.f; tv[j][k][1] = 0.f; }
#pragma unroll
                for (int p = 0; p < P_; ++p) {
                    float2 w = *(const float2*)(Wb + k * 2 * NSTR_ + p * D_);
#pragma unroll
                    for (int j = 0; j < 4; ++j) {
                        tv[j][k][0] = fmaf(w.x, xr[j][p], tv[j][k][0]);
                        tv[j][k][1] = fmaf(w.y, xr[j][p], tv[j][k][1]);
                    }
                }
            }

            if (uni) {
#pragma unroll
                for (int j = 0; j < 4; ++j)
#pragma unroll
                    for (int k = 0; k < 5; ++k) {
                        acc[j][k][0] += tv[j][k][0];
                        acc[j][k][1] += tv[j][k][1];
                    }
            } else {
#pragma unroll
                for (int j = 0; j < 4; ++j) {
                    float e[5];
                    float m = -1e30f;
#pragma unroll
                    for (int k = 0; k < 5; ++k) {
                        float l = fmaf(tv[j][k][1], vc[j][k][1],
                                       tv[j][k][0] * vc[j][k][0]);
                        l += dpp_bcast<0xB1>(l);
                        l += dpp_bcast<0x4E>(l);
                        l += dpp_bcast<0x141>(l);   // full d-dot across 8 ds lanes
                        e[k] = l;
                        m = fmaxf(m, l);
                    }
                    m = fmaxf(m, dpp_bcast<0x140>(m));   // max over other parity
                    float se = 0.f;
#pragma unroll
                    for (int k = 0; k < 5; ++k) { e[k] = __expf(e[k] - m); se += e[k]; }
                    se += dpp_bcast<0x140>(se);
                    float inv = 1.f / se;
#pragma unroll
                    for (int k = 0; k < 5; ++k) {
                        float cn = e[k] * inv;
                        acc[j][k][0] = fmaf(cn, tv[j][k][0], acc[j][k][0]);
                        acc[j][k][1] = fmaf(cn, tv[j][k][1], acc[j][k][1]);
                    }
                }
            }
        }

        // store partials via sc1 (device-coherent), NATURAL layout
#pragma unroll
        for (int j = 0; j < 4; ++j) {
            float* __restrict__ dst = part + (size_t)blockIdx.x * BND_
                                      + (size_t)(bb + j) * ND_ + np * D_ + 2 * ds;
#pragma unroll
            for (int k = 0; k < 5; ++k)
                agent_store_f2(dst + k * 2 * D_, acc[j][k][0], acc[j][k][1]);
        }

        gridbar(cnt, it * 2);   // all partials visible (sc1-acked)

        // ---- R18 balanced reduce: ALL 512 blocks, 20 outputs each ----
        // 240 active threads: fg = f4-group (5), tp = row-group (48; 11/10 rows)
        const int o0 = blockIdx.x * 20;
        if (t < 240) {
            const int fg = t % 5;
            const int tp = t / 5;
            const int r0 = (tp < 32) ? tp * 11 : 352 + (tp - 32) * 10;
            const int rc = (tp < 32) ? 11 : 10;
            float4 s4 = {0.f, 0.f, 0.f, 0.f};
            const float* __restrict__ p0 = part + (size_t)r0 * BND_ + o0 + fg * 4;
            for (int r = 0; r < rc; ++r) {
                float2 a = agent_load_f2(p0 + (size_t)r * BND_);
                float2 b = agent_load_f2(p0 + (size_t)r * BND_ + 2);
                s4.x += a.x; s4.y += a.y; s4.z += b.x; s4.w += b.y;
            }
            rsm4[tp][fg] = s4;
        }
        __syncthreads();
        if (t < 20) {
            const int fg = t >> 2, c = t & 3;
            float tot = 0.f;
#pragma unroll
            for (int tp = 0; tp < 48; ++tp)
                tot += ((const float*)&rsm4[tp][fg])[c];
            tot *= uni ? 0.1f : 1.0f;
            float sq = tot * tot;
            float v = tot * (sq / ((1.f + sq) * sqrtf(sq + EPS_)));
            const int o2 = o0 + t;
            if (it == 0)      { vprev = v;   agent_store_f(Vc + o2, vprev); }
            else if (it == 1) { vprev += v;  agent_store_f(Vc + o2, vprev); }
            else              out[o2] = v;   // plain store: kernel-end writeback
        }

        if (it < 2) gridbar(cnt, it * 2 + 1);  // Vc visible to next pass
    }
}

extern "C" void kernel_launch(void* const* d_in, const int* in_sizes, int n_in,
                              void* d_out, int out_size, void* d_ws, size_t ws_size,
                              hipStream_t stream)
{
    const float* x = (const float*)d_in[0];   // [64, 4096, 8] f32
    const float* W = (const float*)d_in[1];   // [4096, 10, 8, 16] f32
    float* out = (float*)d_out;               // [64, 10, 1, 16] f32

    // ws: part (512*10240 f = 21 MB) | Vc (10240 f) | cnt (5 slots x 17 lines)
    float* part = (float*)d_ws;
    float* Vc   = part + (size_t)NBLK_ * BND_;
    unsigned* cnt = (unsigned*)(Vc + BND_);

    // zero barrier counters (tree epoch math needs consistent init; poison
    // is not guaranteed zero). Graph-capturable async memset.
    hipMemsetAsync(cnt, 0, NSLOT_ * SLOTW_ * sizeof(unsigned), stream);

    digitcaps_fused<<<dim3(NBLK_), dim3(256), 0, stream>>>(x, W, part, Vc, out, cnt);
}